// Round 3
// baseline (3482.294 us; speedup 1.0000x reference)
//
#include <hip/hip_runtime.h>
#include <hip/hip_bf16.h>
#include <stdint.h>

typedef unsigned short ushort_t;
typedef __attribute__((ext_vector_type(8))) short short8;
typedef __attribute__((ext_vector_type(4))) float f32x4;

#define TT 1024
#define BB 128
#define NG 400   // 4*H
#define HID 100

#define ALIGN256(x) ((((size_t)(x)) + 255) & ~(size_t)255)

// ---------------- ws layout (bytes) ----------------
static const size_t WS_FLAG = 0;                                  // int: 1=bf16 inputs, 0=fp32
static const size_t WS_XC   = 256;                                // x copy      13,107,200 el
static const size_t WS_W0C  = WS_XC  + (size_t)13107200 * 2;      // wih0 copy       80,000 el
static const size_t WS_H0C  = WS_W0C + (size_t)80000 * 2;         // whh0 copy       80,000 el
static const size_t WS_B0C  = WS_H0C + (size_t)80000 * 2;         // b0 copy            800 el
static const size_t WS_W1C  = WS_B0C + (size_t)800 * 2;           // wih1 copy      160,000 el
static const size_t WS_H1C  = WS_W1C + (size_t)160000 * 2;        // whh1 copy       80,000 el
static const size_t WS_B1C  = WS_H1C + (size_t)80000 * 2;         // b1 copy            800 el
static const size_t WS_XT   = ALIGN256(WS_B1C + 800 * 2);         // (1024,128,128) bf16
static const size_t WS_OUT0 = WS_XT   + (size_t)1024 * 128 * 128 * 2;  // (1024,128,256) bf16
static const size_t WS_GX   = WS_OUT0 + (size_t)1024 * 128 * 256 * 2;  // (2,1024*128,400) bf16
static const size_t WS_WIH0 = WS_GX   + (size_t)2 * 1024 * 128 * 400 * 2; // (2,400,128) bf16
static const size_t WS_WHH  = WS_WIH0 + (size_t)2 * 400 * 128 * 2;        // (2,2,400,128) bf16
static const size_t WS_WIH1 = WS_WHH  + (size_t)2 * 2 * 400 * 128 * 2;    // (2,400,256) bf16
static const size_t WS_BIAS = WS_WIH1 + (size_t)2 * 400 * 256 * 2;        // (2,2,400) f32

// ---------------- helpers ----------------
__device__ __forceinline__ float bf2f(ushort_t v) {
  return __builtin_bit_cast(float, ((unsigned)v) << 16);
}
__device__ __forceinline__ ushort_t f2bf(float f) {
  unsigned u = __builtin_bit_cast(unsigned, f);
  u += 0x7FFF + ((u >> 16) & 1);   // RNE
  return (ushort_t)(u >> 16);
}
__device__ __forceinline__ float fexp2(float x) {
#if __has_builtin(__builtin_amdgcn_exp2f)
  return __builtin_amdgcn_exp2f(x);
#else
  return __exp2f(x);
#endif
}
__device__ __forceinline__ float frcp(float x) {
#if __has_builtin(__builtin_amdgcn_rcpf)
  return __builtin_amdgcn_rcpf(x);
#else
  return 1.0f / x;
#endif
}
__device__ __forceinline__ float sigm(float x) {
  return frcp(1.0f + fexp2(-1.44269504f * x));
}
__device__ __forceinline__ float tanh_(float x) {
  return 1.0f - 2.0f * frcp(1.0f + fexp2(2.88539008f * x));
}
template<int C>
__device__ __forceinline__ float qbcast(float v) {  // quad_perm broadcast lane C of each 4-lane group
  return __builtin_bit_cast(float,
      __builtin_amdgcn_mov_dpp(__builtin_bit_cast(int, v), C, 0xf, 0xf, true));
}

// ---------------- input dtype detection ----------------
__global__ __launch_bounds__(256) void detect_dtype(const ushort_t* __restrict__ x,
                                                    int* __restrict__ flag) {
  __shared__ int cnt;
  if (threadIdx.x == 0) cnt = 0;
  __syncthreads();
  int local = 0;
  for (int i = threadIdx.x; i < 4096; i += 256) {
    ushort_t u = x[2 * i];
    int e = (u >> 7) & 0xFF;
    if (e >= 0x66 && e <= 0x85) local++;
  }
  atomicAdd(&cnt, local);
  __syncthreads();
  if (threadIdx.x == 0) *flag = (cnt >= 2048) ? 1 : 0;
}

// ---------------- dtype-flexible copy to bf16 ----------------
__global__ __launch_bounds__(256) void cvt_tensor(const ushort_t* __restrict__ src,
                                                  ushort_t* __restrict__ dst, int n,
                                                  const int* __restrict__ flag) {
  int i = blockIdx.x * blockDim.x + threadIdx.x;
  if (i >= n) return;
  if (*flag) {                       // already bf16: copy
    dst[i] = src[i];
  } else {                           // fp32: recombine halves, RNE to bf16
    unsigned lo = src[2 * i];
    unsigned hi = src[2 * i + 1];
    unsigned u = (hi << 16) | lo;
    u += 0x7FFF + ((u >> 16) & 1);
    dst[i] = (ushort_t)(u >> 16);
  }
}

// ---------------- weight prep ----------------
// Gate permutation: np = 4*j + g  <->  n = g*100 + j  (torch order i,f,g,o)
__global__ __launch_bounds__(256) void prep_weights(
    const ushort_t* __restrict__ wih0, const ushort_t* __restrict__ whh0,
    const ushort_t* __restrict__ b0,   const ushort_t* __restrict__ wih1,
    const ushort_t* __restrict__ whh1, const ushort_t* __restrict__ b1,
    ushort_t* __restrict__ WIH0, ushort_t* __restrict__ WHH,
    ushort_t* __restrict__ WIH1, float* __restrict__ BIAS)
{
  int tid = blockIdx.x * blockDim.x + threadIdx.x;
  int nth = gridDim.x * blockDim.x;
  for (int idx = tid; idx < 2 * NG * 128; idx += nth) {          // WIH0 [d][np][k]
    int k = idx & 127; int np = (idx >> 7) % NG; int d = idx / (NG * 128);
    int n = (np & 3) * HID + (np >> 2);
    WIH0[idx] = (k < HID) ? wih0[(size_t)(d * NG + n) * 100 + k] : (ushort_t)0;
  }
  for (int idx = tid; idx < 2 * 2 * NG * 128; idx += nth) {      // WHH [l][d][np][k]
    int k = idx & 127; int np = (idx >> 7) % NG; int dl = idx / (NG * 128);
    int d = dl & 1; int l = dl >> 1;
    int n = (np & 3) * HID + (np >> 2);
    const ushort_t* src = l ? whh1 : whh0;
    WHH[idx] = (k < HID) ? src[(size_t)(d * NG + n) * 100 + k] : (ushort_t)0;
  }
  for (int idx = tid; idx < 2 * NG * 256; idx += nth) {          // WIH1 [d][np][k]
    int k = idx & 255; int np = (idx >> 8) % NG; int d = idx / (NG * 256);
    int n = (np & 3) * HID + (np >> 2);
    int c = (k < 100) ? k : ((k >= 128 && k < 228) ? (k - 28) : -1);
    WIH1[idx] = (c >= 0) ? wih1[(size_t)(d * NG + n) * 200 + c] : (ushort_t)0;
  }
  for (int idx = tid; idx < 2 * 2 * NG; idx += nth) {            // BIAS [l][d][np] f32
    int np = idx % NG; int dl = idx / NG; int d = dl & 1; int l = dl >> 1;
    int n = (np & 3) * HID + (np >> 2);
    BIAS[idx] = bf2f(l ? b1[d * NG + n] : b0[d * NG + n]);
  }
}

// ---------------- pack x: (B,100,T) -> xT (T,B,128) zero-padded ----------------
__global__ __launch_bounds__(256) void pack_x(const ushort_t* __restrict__ x,
                                              ushort_t* __restrict__ xT)
{
  __shared__ ushort_t tile[100][68];
  const int b = blockIdx.x;
  const int t0 = blockIdx.y << 6;
  for (int i = threadIdx.x; i < 100 * 64; i += 256) {
    int k = i >> 6, t = i & 63;
    tile[k][t] = x[((size_t)b * 100 + k) * TT + t0 + t];
  }
  __syncthreads();
  for (int i = threadIdx.x; i < 128 * 64; i += 256) {
    int k = i & 127, t = i >> 7;
    xT[((size_t)(t0 + t) * BB + b) * 128 + k] = (k < 100) ? tile[k][t] : (ushort_t)0;
  }
}

// ---------------- gx GEMM: gx[d][row][np] = A[row][:] @ W[d][np][:]^T + bias ----------------
__global__ __launch_bounds__(256) void gemm_gx(
    const ushort_t* __restrict__ A, const ushort_t* __restrict__ W,
    const float* __restrict__ BIASL, ushort_t* __restrict__ gxo, int kpad)
{
  const int mtile = blockIdx.x;
  const int d = blockIdx.y;
  const int w = threadIdx.x >> 6;
  const int lane = threadIdx.x & 63;
  const int quad = lane >> 4;
  const int lm = lane & 15;
  const int m0 = mtile * 16;
  const int nkt = kpad >> 5;

  f32x4 acc[7];
#pragma unroll
  for (int i = 0; i < 7; i++) acc[i] = (f32x4){0.f, 0.f, 0.f, 0.f};

  const ushort_t* Wd = W + (size_t)d * NG * kpad;
  const ushort_t* Ap = A + (size_t)(m0 + lm) * kpad + quad * 8;

  for (int kt = 0; kt < nkt; kt++) {
    short8 a = *(const short8*)(Ap + kt * 32);
#pragma unroll
    for (int i = 0; i < 7; i++) {
      int nt = w + 4 * i; if (nt >= 25) nt = 0;   // redundant compute, store skipped
      short8 bb = *(const short8*)(Wd + (size_t)(nt * 16 + lm) * kpad + kt * 32 + quad * 8);
      acc[i] = __builtin_amdgcn_mfma_f32_16x16x32_bf16(a, bb, acc[i], 0, 0, 0);
    }
  }

  ushort_t* go = gxo + ((size_t)d * TT * BB + m0) * NG;
  const float* bd = BIASL + d * NG;
#pragma unroll
  for (int i = 0; i < 7; i++) {
    int nt = w + 4 * i;
    if (nt >= 25) break;                           // wave-uniform
    int n = nt * 16 + lm;
    float bias = bd[n];
#pragma unroll
    for (int r = 0; r < 4; r++)
      go[(size_t)(quad * 4 + r) * NG + n] = f2bf(acc[i][r] + bias);
  }
}

// ---------------- recurrent LSTM layer (both directions in one launch) ----------------
// grid: 16 blocks = 2 dirs x 8 row-groups of 16 batch rows; 512 threads = 8 waves.
// Wave w owns N-tiles {w, w+8, w+16} (+24 for w==0). One barrier per step.
// F32OUT: final layer writes fp32 to d_out; layer 0 writes bf16 to internal out0.
template<bool F32OUT>
__global__ __launch_bounds__(512, 1) void lstm_layer(
    const ushort_t* __restrict__ gx, const ushort_t* __restrict__ WHHl,
    void* __restrict__ outp, int ostride, int colmult)
{
  const int dir = blockIdx.x >> 3;
  const int b0 = (blockIdx.x & 7) << 4;
  const int w = threadIdx.x >> 6;
  const int lane = threadIdx.x & 63;
  const int quad = lane >> 4;
  const int lm = lane & 15;
  const int g = lane & 3;          // gate type of this lane's C column
  const int jj = (lane >> 2) & 3;  // hidden-unit sub-index within tile
  const int ocol = dir * colmult;

  __shared__ ushort_t hbuf[2][16][136];   // h double-buffer, bf16, K padded to 128, stride 136
  for (int i = threadIdx.x; i < 2 * 16 * 136; i += 512) ((ushort_t*)hbuf)[i] = 0;

  // persistent W_hh B-fragments
  short8 bfrag[4][4];
#pragma unroll
  for (int i = 0; i < 4; i++) {
    int nt = (i < 3) ? (w + 8 * i) : 24;
    const ushort_t* wp = WHHl + ((size_t)dir * NG + nt * 16 + lm) * 128;
#pragma unroll
    for (int kt = 0; kt < 4; kt++)
      bfrag[i][kt] = *(const short8*)(wp + kt * 32 + quad * 8);
  }

  float cst[4] = {0.f, 0.f, 0.f, 0.f};    // cell state, one item (m,j) per lane per tile
  const ushort_t* gxd = gx + (size_t)dir * TT * BB * NG;

  ushort_t pf[4][4];                       // gx prefetch for next step
  {
    int tt0 = dir ? (TT - 1) : 0;
#pragma unroll
    for (int i = 0; i < 4; i++) {
      int nt = (i < 3) ? (w + 8 * i) : 24;
#pragma unroll
      for (int r = 0; r < 4; r++)
        pf[i][r] = gxd[((size_t)tt0 * BB + b0 + quad * 4 + r) * NG + nt * 16 + lm];
    }
  }

  __syncthreads();

  for (int t = 0; t < TT; t++) {
    const int tt = dir ? (TT - 1 - t) : t;
    const int pb = t & 1;

    // init accumulators from prefetched gx (C layout: m=quad*4+r, n=16nt+lm)
    f32x4 acc[4];
#pragma unroll
    for (int i = 0; i < 4; i++) {
#pragma unroll
      for (int r = 0; r < 4; r++) acc[i][r] = bf2f(pf[i][r]);
    }

    // prefetch next step's gx (overlaps MFMA + epilogue)
    if (t + 1 < TT) {
      int tn = dir ? (TT - 2 - t) : (t + 1);
#pragma unroll
      for (int i = 0; i < 4; i++) {
        int nt = (i < 3) ? (w + 8 * i) : 24;
#pragma unroll
        for (int r = 0; r < 4; r++)
          pf[i][r] = gxd[((size_t)tn * BB + b0 + quad * 4 + r) * NG + nt * 16 + lm];
      }
    }

    // A fragments: h rows (m=lm), 8 consecutive k per lane
    short8 afr[4];
#pragma unroll
    for (int kt = 0; kt < 4; kt++)
      afr[kt] = *(const short8*)(&hbuf[pb][lm][kt * 32 + quad * 8]);

#pragma unroll
    for (int i = 0; i < 4; i++) {
      if (i == 3 && w != 0) continue;      // wave-uniform
#pragma unroll
      for (int kt = 0; kt < 4; kt++)
        acc[i] = __builtin_amdgcn_mfma_f32_16x16x32_bf16(afr[kt], bfrag[i][kt], acc[i], 0, 0, 0);
    }

    // epilogue: each 4-lane quad holds (i,f,g,o) of one (m,j) item per reg
#pragma unroll
    for (int i = 0; i < 4; i++) {
      if (i == 3 && w != 0) continue;
      float vi = 0.f, vf = 0.f, vg = 0.f, vo = 0.f;
#pragma unroll
      for (int r = 0; r < 4; r++) {
        float v = acc[i][r];
        float s0 = qbcast<0x00>(v);
        float s1 = qbcast<0x55>(v);
        float s2 = qbcast<0xAA>(v);
        float s3 = qbcast<0xFF>(v);
        bool sel = (g == r);
        vi = sel ? s0 : vi;
        vf = sel ? s1 : vf;
        vg = sel ? s2 : vg;
        vo = sel ? s3 : vo;
      }
      int nt = (i < 3) ? (w + 8 * i) : 24;
      int j = 4 * nt + jj;
      int m = quad * 4 + g;
      float cn = sigm(vf) * cst[i] + sigm(vi) * tanh_(vg);
      cst[i] = cn;
      float h = sigm(vo) * tanh_(cn);
      hbuf[pb ^ 1][m][j] = f2bf(h);
      size_t oidx = ((size_t)tt * BB + b0 + m) * ostride + ocol + j;
      if (F32OUT) ((float*)outp)[oidx] = h;
      else        ((ushort_t*)outp)[oidx] = f2bf(h);
    }
    __syncthreads();
  }
}

// ---------------- launch ----------------
extern "C" void kernel_launch(void* const* d_in, const int* in_sizes, int n_in,
                              void* d_out, int out_size, void* d_ws, size_t ws_size,
                              hipStream_t stream) {
  const ushort_t* x_raw    = (const ushort_t*)d_in[0];
  const ushort_t* wih0_raw = (const ushort_t*)d_in[1];
  const ushort_t* whh0_raw = (const ushort_t*)d_in[2];
  const ushort_t* b0_raw   = (const ushort_t*)d_in[3];
  const ushort_t* wih1_raw = (const ushort_t*)d_in[4];
  const ushort_t* whh1_raw = (const ushort_t*)d_in[5];
  const ushort_t* b1_raw   = (const ushort_t*)d_in[6];

  char* ws = (char*)d_ws;
  int*      FLAG = (int*)(ws + WS_FLAG);
  ushort_t* xc   = (ushort_t*)(ws + WS_XC);
  ushort_t* w0c  = (ushort_t*)(ws + WS_W0C);
  ushort_t* h0c  = (ushort_t*)(ws + WS_H0C);
  ushort_t* b0c  = (ushort_t*)(ws + WS_B0C);
  ushort_t* w1c  = (ushort_t*)(ws + WS_W1C);
  ushort_t* h1c  = (ushort_t*)(ws + WS_H1C);
  ushort_t* b1c  = (ushort_t*)(ws + WS_B1C);
  ushort_t* xT   = (ushort_t*)(ws + WS_XT);
  ushort_t* out0 = (ushort_t*)(ws + WS_OUT0);
  ushort_t* gx   = (ushort_t*)(ws + WS_GX);
  ushort_t* WIH0 = (ushort_t*)(ws + WS_WIH0);
  ushort_t* WHH  = (ushort_t*)(ws + WS_WHH);
  ushort_t* WIH1 = (ushort_t*)(ws + WS_WIH1);
  float*    BIAS = (float*)(ws + WS_BIAS);

  // 1) detect input dtype (data-dependent only -> graph-safe)
  detect_dtype<<<1, 256, 0, stream>>>(x_raw, FLAG);

  // 2) materialize bf16 copies of all inputs
  cvt_tensor<<<(13107200 + 255) / 256, 256, 0, stream>>>(x_raw,    xc,  13107200, FLAG);
  cvt_tensor<<<(80000    + 255) / 256, 256, 0, stream>>>(wih0_raw, w0c, 80000,    FLAG);
  cvt_tensor<<<(80000    + 255) / 256, 256, 0, stream>>>(whh0_raw, h0c, 80000,    FLAG);
  cvt_tensor<<<(800      + 255) / 256, 256, 0, stream>>>(b0_raw,   b0c, 800,      FLAG);
  cvt_tensor<<<(160000   + 255) / 256, 256, 0, stream>>>(wih1_raw, w1c, 160000,   FLAG);
  cvt_tensor<<<(80000    + 255) / 256, 256, 0, stream>>>(whh1_raw, h1c, 80000,    FLAG);
  cvt_tensor<<<(800      + 255) / 256, 256, 0, stream>>>(b1_raw,   b1c, 800,      FLAG);

  // 3) pipeline (all bf16 internally)
  prep_weights<<<256, 256, 0, stream>>>(w0c, h0c, b0c, w1c, h1c, b1c,
                                        WIH0, WHH, WIH1, BIAS);
  pack_x<<<dim3(128, 16), 256, 0, stream>>>(xc, xT);
  // layer 0 (bf16 internal output)
  gemm_gx<<<dim3(8192, 2), 256, 0, stream>>>(xT, WIH0, BIAS, gx, 128);
  lstm_layer<false><<<16, 512, 0, stream>>>(gx, WHH, out0, 256, 128);
  // layer 1 (fp32 output to d_out, matching reference output dtype)
  gemm_gx<<<dim3(8192, 2), 256, 0, stream>>>(out0, WIH1, BIAS + 2 * NG, gx, 256);
  lstm_layer<true><<<16, 512, 0, stream>>>(gx, WHH + (size_t)2 * NG * 128, d_out, 200, 100);
}

// Round 4
// 3039.401 us; speedup vs baseline: 1.1457x; 1.1457x over previous
//
#include <hip/hip_runtime.h>
#include <hip/hip_bf16.h>
#include <stdint.h>

typedef unsigned short ushort_t;
typedef __attribute__((ext_vector_type(8))) short short8;
typedef __attribute__((ext_vector_type(4))) short short4_t;
typedef __attribute__((ext_vector_type(4))) float f32x4;

#define TT 1024
#define BB 128
#define NG 400   // 4*H
#define HID 100

#define ALIGN256(x) ((((size_t)(x)) + 255) & ~(size_t)255)

// ---------------- ws layout (bytes) ----------------
static const size_t WS_FLAG = 0;                                  // int: 1=bf16 inputs, 0=fp32
static const size_t WS_XT   = 4096;                               // (1024,128,128) bf16
static const size_t WS_OUT0 = WS_XT   + (size_t)1024 * 128 * 128 * 2;  // (1024,128,256) bf16
static const size_t WS_GX   = WS_OUT0 + (size_t)1024 * 128 * 256 * 2;  // (2,1024,8,6400) bf16 permuted
static const size_t WS_WIH0 = WS_GX   + (size_t)2 * 1024 * 128 * 400 * 2; // (2,400,128) bf16
static const size_t WS_WHH  = WS_WIH0 + (size_t)2 * 400 * 128 * 2;        // (2,2,400,128) bf16
static const size_t WS_WIH1 = WS_WHH  + (size_t)2 * 2 * 400 * 128 * 2;    // (2,400,256) bf16
static const size_t WS_BIAS = WS_WIH1 + (size_t)2 * 400 * 256 * 2;        // (2,2,400) f32

// ---------------- helpers ----------------
__device__ __forceinline__ float bf2f(ushort_t v) {
  return __builtin_bit_cast(float, ((unsigned)v) << 16);
}
__device__ __forceinline__ ushort_t f2bf(float f) {
  unsigned u = __builtin_bit_cast(unsigned, f);
  u += 0x7FFF + ((u >> 16) & 1);   // RNE
  return (ushort_t)(u >> 16);
}
// flag-based load: bf16 passthrough or fp32->bf16
__device__ __forceinline__ ushort_t ldbf(const void* p, size_t i, int isbf) {
  return isbf ? ((const ushort_t*)p)[i] : f2bf(((const float*)p)[i]);
}
__device__ __forceinline__ float ldf(const void* p, size_t i, int isbf) {
  return isbf ? bf2f(((const ushort_t*)p)[i]) : ((const float*)p)[i];
}
__device__ __forceinline__ float fexp2(float x) {
#if __has_builtin(__builtin_amdgcn_exp2f)
  return __builtin_amdgcn_exp2f(x);
#else
  return __exp2f(x);
#endif
}
__device__ __forceinline__ float frcp(float x) {
#if __has_builtin(__builtin_amdgcn_rcpf)
  return __builtin_amdgcn_rcpf(x);
#else
  return 1.0f / x;
#endif
}
__device__ __forceinline__ float sigm(float x) {
  return frcp(1.0f + fexp2(-1.44269504f * x));
}
__device__ __forceinline__ float tanh_(float x) {
  return 1.0f - 2.0f * frcp(1.0f + fexp2(2.88539008f * x));
}

// ---------------- input dtype detection ----------------
__global__ __launch_bounds__(256) void detect_dtype(const ushort_t* __restrict__ x,
                                                    int* __restrict__ flag) {
  __shared__ int cnt;
  if (threadIdx.x == 0) cnt = 0;
  __syncthreads();
  int local = 0;
  for (int i = threadIdx.x; i < 4096; i += 256) {
    ushort_t u = x[2 * i];
    int e = (u >> 7) & 0xFF;
    if (e >= 0x66 && e <= 0x85) local++;
  }
  atomicAdd(&cnt, local);
  __syncthreads();
  if (threadIdx.x == 0) *flag = (cnt >= 2048) ? 1 : 0;
}

// ---------------- weight prep (reads raw fp32-or-bf16 via flag) ----------------
// Gate permutation: np = 4*j + g  <->  n = g*100 + j  (torch order i,f,g,o)
__global__ __launch_bounds__(256) void prep_weights(
    const void* __restrict__ wih0, const void* __restrict__ whh0,
    const void* __restrict__ b0,   const void* __restrict__ wih1,
    const void* __restrict__ whh1, const void* __restrict__ b1,
    ushort_t* __restrict__ WIH0, ushort_t* __restrict__ WHH,
    ushort_t* __restrict__ WIH1, float* __restrict__ BIAS,
    const int* __restrict__ flag)
{
  const int isbf = *flag;
  int tid = blockIdx.x * blockDim.x + threadIdx.x;
  int nth = gridDim.x * blockDim.x;
  for (int idx = tid; idx < 2 * NG * 128; idx += nth) {          // WIH0 [d][np][k]
    int k = idx & 127; int np = (idx >> 7) % NG; int d = idx / (NG * 128);
    int n = (np & 3) * HID + (np >> 2);
    WIH0[idx] = (k < HID) ? ldbf(wih0, (size_t)(d * NG + n) * 100 + k, isbf) : (ushort_t)0;
  }
  for (int idx = tid; idx < 2 * 2 * NG * 128; idx += nth) {      // WHH [l][d][np][k]
    int k = idx & 127; int np = (idx >> 7) % NG; int dl = idx / (NG * 128);
    int d = dl & 1; int l = dl >> 1;
    int n = (np & 3) * HID + (np >> 2);
    const void* src = l ? whh1 : whh0;
    WHH[idx] = (k < HID) ? ldbf(src, (size_t)(d * NG + n) * 100 + k, isbf) : (ushort_t)0;
  }
  for (int idx = tid; idx < 2 * NG * 256; idx += nth) {          // WIH1 [d][np][k]
    int k = idx & 255; int np = (idx >> 8) % NG; int d = idx / (NG * 256);
    int n = (np & 3) * HID + (np >> 2);
    int c = (k < 100) ? k : ((k >= 128 && k < 228) ? (k - 28) : -1);
    WIH1[idx] = (c >= 0) ? ldbf(wih1, (size_t)(d * NG + n) * 200 + c, isbf) : (ushort_t)0;
  }
  for (int idx = tid; idx < 2 * 2 * NG; idx += nth) {            // BIAS [l][d][np] f32
    int np = idx % NG; int dl = idx / NG; int d = dl & 1; int l = dl >> 1;
    int n = (np & 3) * HID + (np >> 2);
    BIAS[idx] = ldf(l ? b1 : b0, d * NG + n, isbf);
  }
}

// ---------------- pack x: (B,100,T) raw -> xT (T,B,128) bf16 zero-padded ----------------
__global__ __launch_bounds__(256) void pack_x(const void* __restrict__ x,
                                              ushort_t* __restrict__ xT,
                                              const int* __restrict__ flag)
{
  __shared__ ushort_t tile[100][68];
  const int isbf = *flag;
  const int b = blockIdx.x;
  const int t0 = blockIdx.y << 6;
  for (int i = threadIdx.x; i < 100 * 64; i += 256) {
    int k = i >> 6, t = i & 63;
    tile[k][t] = ldbf(x, ((size_t)b * 100 + k) * TT + t0 + t, isbf);
  }
  __syncthreads();
  for (int i = threadIdx.x; i < 128 * 64; i += 256) {
    int k = i & 127, t = i >> 7;
    xT[((size_t)(t0 + t) * BB + b) * 128 + k] = (k < 100) ? tile[k][t] : (ushort_t)0;
  }
}

// ---------------- gx GEMM: writes permuted gx layout ----------------
// gx block for (d,t,bg): 6400 ushorts, inner = (nt*64 + lm_rec*4 + quad_rec)*4 + gamma
// where lm_rec = batch row in 16, quad_rec = unit sub (0..3), gamma = gate (0..3).
__global__ __launch_bounds__(256) void gemm_gx(
    const ushort_t* __restrict__ A, const ushort_t* __restrict__ W,
    const float* __restrict__ BIASL, ushort_t* __restrict__ gxo, int kpad)
{
  const int mtile = blockIdx.x;        // 0..8191: t = mtile>>3, bg = mtile&7
  const int d = blockIdx.y;
  const int w = threadIdx.x >> 6;
  const int lane = threadIdx.x & 63;
  const int quad = lane >> 4;
  const int lm = lane & 15;
  const int m0 = mtile * 16;
  const int nkt = kpad >> 5;

  f32x4 acc[7];
#pragma unroll
  for (int i = 0; i < 7; i++) acc[i] = (f32x4){0.f, 0.f, 0.f, 0.f};

  const ushort_t* Wd = W + (size_t)d * NG * kpad;
  const ushort_t* Ap = A + (size_t)(m0 + lm) * kpad + quad * 8;

  for (int kt = 0; kt < nkt; kt++) {
    short8 a = *(const short8*)(Ap + kt * 32);
#pragma unroll
    for (int i = 0; i < 7; i++) {
      int nt = w + 4 * i; if (nt >= 25) nt = 0;   // redundant compute, store skipped
      short8 bb = *(const short8*)(Wd + (size_t)(nt * 16 + lm) * kpad + kt * 32 + quad * 8);
      acc[i] = __builtin_amdgcn_mfma_f32_16x16x32_bf16(a, bb, acc[i], 0, 0, 0);
    }
  }

  const int t = mtile >> 3, bg = mtile & 7;
  ushort_t* go = gxo + (((size_t)d * TT + t) * 8 + bg) * 6400;
  const float* bd = BIASL + d * NG;
  const int qr = lm >> 2, gam = lm & 3;
#pragma unroll
  for (int i = 0; i < 7; i++) {
    int nt = w + 4 * i;
    if (nt >= 25) break;                           // wave-uniform
    int n = nt * 16 + lm;
    float bias = bd[n];
#pragma unroll
    for (int r = 0; r < 4; r++)
      go[(nt * 64 + (quad * 4 + r) * 4 + qr) * 4 + gam] = f2bf(acc[i][r] + bias);
  }
}

// ---------------- recurrent LSTM layer ----------------
// grid: 16 blocks = 2 dirs x 8 row-groups of 16 batch rows; 512 threads = 8 waves.
// Transposed MFMA: A = W_hh tile (M=16 gate-cols), B = h (N=16 batch rows).
// C layout m=quad*4+r, n=lm  =>  lane (quad,lm) holds gates i,f,g,o of item
// (unit = nt*4+quad, batch = lm) in acc regs 0..3 directly — no gather.
template<bool F32OUT>
__global__ __launch_bounds__(512, 1) void lstm_layer(
    const ushort_t* __restrict__ gx, const ushort_t* __restrict__ WHHl,
    void* __restrict__ outp, int ostride, int colmult)
{
  const int dir = blockIdx.x >> 3;
  const int bg = blockIdx.x & 7;
  const int b0 = bg << 4;
  const int w = threadIdx.x >> 6;
  const int lane = threadIdx.x & 63;
  const int quad = lane >> 4;
  const int lm = lane & 15;
  const int ocol = dir * colmult;

  __shared__ ushort_t hbuf[2][16][136];   // [buf][batch row][unit k], K padded to 128
  for (int i = threadIdx.x; i < 2 * 16 * 136; i += 512) ((ushort_t*)hbuf)[i] = 0;

  // persistent W_hh A-fragments: A[m=np=nt*16+lm][k=quad*8+j]
  short8 afragW[4][4];
  int nts[4];
#pragma unroll
  for (int i = 0; i < 4; i++) {
    int nt = (i < 3) ? (w + 8 * i) : 24;
    nts[i] = nt;
    const ushort_t* wp = WHHl + ((size_t)dir * NG + nt * 16 + lm) * 128;
#pragma unroll
    for (int kt = 0; kt < 4; kt++)
      afragW[i][kt] = *(const short8*)(wp + kt * 32 + quad * 8);
  }

  // per-tile gx lane offsets (ushorts), constant over t
  int loff[4];
#pragma unroll
  for (int i = 0; i < 4; i++) loff[i] = (nts[i] * 64 + lm * 4 + quad) * 4;

  float cst[4] = {0.f, 0.f, 0.f, 0.f};    // cell state: item (unit nts[i]*4+quad, batch lm)
  const ushort_t* gxd = gx + ((size_t)dir * TT * 8 + bg) * 6400;

  short4_t pf[4];                          // gx prefetch (4 gates of item, 8B each)
  {
    int tt0 = dir ? (TT - 1) : 0;
    const ushort_t* gp = gxd + (size_t)tt0 * 8 * 6400;
#pragma unroll
    for (int i = 0; i < 4; i++) pf[i] = *(const short4_t*)(gp + loff[i]);
  }

  __syncthreads();

  for (int t = 0; t < TT; t++) {
    const int tt = dir ? (TT - 1 - t) : t;
    const int pb = t & 1;

    // init accumulators from prefetched gx (reg r == gate gamma)
    f32x4 acc[4];
#pragma unroll
    for (int i = 0; i < 4; i++) {
#pragma unroll
      for (int r = 0; r < 4; r++) acc[i][r] = bf2f((ushort_t)pf[i][r]);
    }

    // prefetch next step's gx (overlaps MFMA + epilogue)
    if (t + 1 < TT) {
      int tn = dir ? (TT - 2 - t) : (t + 1);
      const ushort_t* gp = gxd + (size_t)tn * 8 * 6400;
#pragma unroll
      for (int i = 0; i < 4; i++) pf[i] = *(const short4_t*)(gp + loff[i]);
    }

    // B fragments: h, B[n=batch lm][k=quad*8+j]
    short8 bfr[4];
#pragma unroll
    for (int kt = 0; kt < 4; kt++)
      bfr[kt] = *(const short8*)(&hbuf[pb][lm][kt * 32 + quad * 8]);

#pragma unroll
    for (int i = 0; i < 4; i++) {
      if (i == 3 && w != 0) continue;      // wave-uniform
#pragma unroll
      for (int kt = 0; kt < 4; kt++)
        acc[i] = __builtin_amdgcn_mfma_f32_16x16x32_bf16(afragW[i][kt], bfr[kt], acc[i], 0, 0, 0);
    }

    // epilogue: gates are acc[i][0..3] directly
#pragma unroll
    for (int i = 0; i < 4; i++) {
      if (i == 3 && w != 0) continue;
      float gi = acc[i][0], gf = acc[i][1], gg = acc[i][2], go = acc[i][3];
      float cn = sigm(gf) * cst[i] + sigm(gi) * tanh_(gg);
      cst[i] = cn;
      float h = sigm(go) * tanh_(cn);
      int j = nts[i] * 4 + quad;           // unit index
      hbuf[pb ^ 1][lm][j] = f2bf(h);
      size_t oidx = ((size_t)tt * BB + b0 + lm) * ostride + ocol + j;
      if (F32OUT) ((float*)outp)[oidx] = h;
      else        ((ushort_t*)outp)[oidx] = f2bf(h);
    }
    __syncthreads();
  }
}

// ---------------- launch ----------------
extern "C" void kernel_launch(void* const* d_in, const int* in_sizes, int n_in,
                              void* d_out, int out_size, void* d_ws, size_t ws_size,
                              hipStream_t stream) {
  const void* x_raw    = d_in[0];
  const void* wih0_raw = d_in[1];
  const void* whh0_raw = d_in[2];
  const void* b0_raw   = d_in[3];
  const void* wih1_raw = d_in[4];
  const void* whh1_raw = d_in[5];
  const void* b1_raw   = d_in[6];

  char* ws = (char*)d_ws;
  int*      FLAG = (int*)(ws + WS_FLAG);
  ushort_t* xT   = (ushort_t*)(ws + WS_XT);
  ushort_t* out0 = (ushort_t*)(ws + WS_OUT0);
  ushort_t* gx   = (ushort_t*)(ws + WS_GX);
  ushort_t* WIH0 = (ushort_t*)(ws + WS_WIH0);
  ushort_t* WHH  = (ushort_t*)(ws + WS_WHH);
  ushort_t* WIH1 = (ushort_t*)(ws + WS_WIH1);
  float*    BIAS = (float*)(ws + WS_BIAS);

  // 1) detect input dtype (data-dependent only -> graph-safe)
  detect_dtype<<<1, 256, 0, stream>>>((const ushort_t*)x_raw, FLAG);

  // 2) prep (flag-based inline conversion, no separate cvt passes)
  prep_weights<<<256, 256, 0, stream>>>(wih0_raw, whh0_raw, b0_raw,
                                        wih1_raw, whh1_raw, b1_raw,
                                        WIH0, WHH, WIH1, BIAS, FLAG);
  pack_x<<<dim3(128, 16), 256, 0, stream>>>(x_raw, xT, FLAG);

  // layer 0 (bf16 internal output)
  gemm_gx<<<dim3(8192, 2), 256, 0, stream>>>(xT, WIH0, BIAS, gx, 128);
  lstm_layer<false><<<16, 512, 0, stream>>>(gx, WHH, out0, 256, 128);
  // layer 1 (fp32 output to d_out)
  gemm_gx<<<dim3(8192, 2), 256, 0, stream>>>(out0, WIH1, BIAS + 2 * NG, gx, 256);
  lstm_layer<true><<<16, 512, 0, stream>>>(gx, WHH + (size_t)2 * NG * 128, d_out, 200, 100);
}